// Round 12
// baseline (148.176 us; speedup 1.0000x reference)
//
#include <hip/hip_runtime.h>
#include <cstdint>
#include <cstddef>

#define BATCH  8192
#define DIM    256
#define NSTRIP 8
#define SCOLS  1024           // columns per strip
#define MROWS  128            // rows per block (8 waves x 16 rows)
#define NTILE  32             // cols per inner iteration
#define NITER  (SCOLS/NTILE)  // 32

static constexpr float EXP2_SC = 1.4426950408889634f / 0.07f;  // log2(e)/T
static constexpr float LN2     = 0.6931471805599453f;          // sim = z * LN2
static constexpr float MARGIN  = 0.2f;

typedef __attribute__((ext_vector_type(8))) short short8;
typedef __attribute__((ext_vector_type(4))) float f32x4;

__device__ __forceinline__ unsigned short f2bf(float f){
  unsigned int u = __float_as_uint(f);
  u += 0x7FFFu + ((u >> 16) & 1u);     // round-to-nearest-even
  return (unsigned short)(u >> 16);
}

__device__ __forceinline__ float med3f(float a, float b, float c){
  float r;
  asm("v_med3_f32 %0, %1, %2, %3" : "=v"(r) : "v"(a), "v"(b), "v"(c));
  return r;
}

// insert s into sorted t0>=t1>=t2, keep top-3: 3 VALU ops (max + 2 med3)
__device__ __forceinline__ void ins3(float& t0, float& t1, float& t2, float s){
  const float r1 = med3f(s, t0, t1);   // uses old t0,t1
  const float r2 = med3f(s, t1, t2);   // uses old t1,t2
  t0 = fmaxf(t0, s);
  t1 = r1; t2 = r2;
}

// ---- kernel 1: L2-normalize rows (fp32), cast to bf16; zero scalar accumulators
__global__ void norm_cast_kernel(const float* __restrict__ emb,
                                 unsigned short* __restrict__ E,
                                 float* __restrict__ accum){
  if (blockIdx.x == 0 && threadIdx.x < 8) accum[threadIdx.x] = 0.0f;
  const int wave = threadIdx.x >> 6;
  const int lane = threadIdx.x & 63;
  const int row  = blockIdx.x * 4 + wave;
  const float4 v = *(const float4*)(emb + (size_t)row * DIM + lane * 4);
  float ss = v.x*v.x + v.y*v.y + v.z*v.z + v.w*v.w;
  #pragma unroll
  for (int m = 1; m < 64; m <<= 1) ss += __shfl_xor(ss, m, 64);
  float nrm = fmaxf(sqrtf(ss), 1e-12f);
  float inv = 1.0f / nrm;
  ushort4 o;
  o.x = f2bf(v.x * inv); o.y = f2bf(v.y * inv);
  o.z = f2bf(v.z * inv); o.w = f2bf(v.w * inv);
  *(ushort4*)(E + (size_t)row * DIM + lane * 4) = o;
}

// ---- kernel 2: fused sim-tile GEMM (bf16 MFMA) + online per-row statistics.
// T3/T4 (counted vmcnt, never 0 in loop): ring-4 LDS buffers, prefetch
// distance 3. STEP(t): issue stage(t+3) -> compute buf(t) -> vmcnt(4)
// (waits only tile t+1; t+2,t+3 stay in flight ACROSS the barrier) ->
// s_barrier. This removes the full-drain stall every config shared
// (R6/R9/R10/R11 invariant ~11Kcyc/iter vs ~7Kcyc busy-sum).
// Geometry = R9's verified zero-conflict staging/compute: 512thr, 8 waves
// x 16 rows, NTILE=32; grid (8,64)=512 = 2 blocks/CU exact (LDS 68KB).
__global__ __launch_bounds__(512, 4)
void sim_stats_kernel(const unsigned short* __restrict__ E,
                      const int* __restrict__ labels,
                      float* __restrict__ partials){
  const int strip = blockIdx.x;
  const int cs    = strip * SCOLS;
  const int tid   = threadIdx.x;
  const int wave  = tid >> 6;
  const int lane  = tid & 63;
  const int l     = lane & 15;   // column within 16-wide subtile
  const int q     = lane >> 4;   // quad: selects k-group and C row group

  // ring-4 B buffers: [chunk c=(kk*4+q) 0..31][col r 0..31] of 8 bf16 (16B)
  __shared__ short8 Bs0[32 * 32];   // 16 KiB
  __shared__ short8 Bs1[32 * 32];   // 16 KiB
  __shared__ short8 Bs2[32 * 32];   // 16 KiB
  __shared__ short8 Bs3[32 * 32];   // 16 KiB
  __shared__ int labs[SCOLS];       // 4 KiB

  for (int i = tid; i < SCOLS; i += 512) labs[i] = labels[cs + i];

  const int row0 = blockIdx.y * MROWS + wave * 16;

  // async stage of one 32-col tile (16KB): 2 insts/wave, each covers 2 chunks
  // (lane>>5 picks chunk half, lane&31 picks col). Verified zero-conflict
  // R9 form: per-inst addr, offset=0; LDS dst = wave-uniform base + lane*16.
  auto stage = [&](short8* dstBuf, int it){
    const int cb  = cs + it * NTILE;
    const int col = lane & 31;
    const int hf  = lane >> 5;
    #pragma unroll
    for (int ii = 0; ii < 2; ++ii){
      const int cpair = wave * 4 + ii * 2;
      const unsigned short* g = E + (size_t)(cb + col) * DIM + (cpair + hf) * 8;
      __builtin_amdgcn_global_load_lds(
        (const __attribute__((address_space(1))) unsigned int*)g,
        (__attribute__((address_space(3))) unsigned int*)&dstBuf[cpair * 32],
        16, 0, 0);
    }
  };

  // prologue: fill the ring 3 deep
  stage(Bs0, 0); stage(Bs1, 1); stage(Bs2, 2);

  // A fragments for the wave's 16 rows, full K=256, kept in registers (32 VGPR).
  short8 a[8];
  {
    const unsigned short* rp = E + (size_t)(row0 + l) * DIM + q * 8;
    #pragma unroll
    for (int kk = 0; kk < 8; ++kk)
      a[kk] = *(const short8*)(rp + kk * 32);
  }

  int labr[4];
  #pragma unroll
  for (int rr = 0; rr < 4; ++rr)
    labr[rr] = labels[row0 + q * 4 + rr];

  float all_s[4], pos_s[4], pos_m[4], t0[4], t1[4], t2[4];
  #pragma unroll
  for (int s = 0; s < 4; ++s){
    all_s[s] = 0.f; pos_s[s] = 0.f;
    pos_m[s] = -INFINITY; t0[s] = -INFINITY; t1[s] = -INFINITY; t2[s] = -INFINITY;
  }

  auto compute = [&](const short8* B, int it){
    const int cb = cs + it * NTILE;
    #pragma unroll
    for (int t = 0; t < 2; ++t){
      const int c0   = cb + t * 16;
      const int labc = labs[it * NTILE + t * 16 + l];
      f32x4 acc = {0.f,0.f,0.f,0.f};
      #pragma unroll
      for (int kk = 0; kk < 8; ++kk){
        short8 b = B[(kk * 4 + q) * 32 + t * 16 + l];
        acc = __builtin_amdgcn_mfma_f32_16x16x32_bf16(a[kk], b, acc, 0, 0, 0);
      }
      // wave-uniform: 16-aligned subtile hits the wave's 16 rows iff equal
      const bool selfT = (c0 == row0);
      #pragma unroll
      for (int rr = 0; rr < 4; ++rr){
        const float d  = acc[rr];
        const float z  = d * EXP2_SC;                    // z-space maxima
        const float ex = __builtin_amdgcn_exp2f(z);
        const bool same = (labc == labr[rr]);
        bool  ispos = same;
        float exa   = ex;
        if (selfT){
          const int grow = row0 + q * 4 + rr;
          const bool self = (c0 + l == grow);
          ispos = same && !self;
          exa   = self ? 0.f : ex;
        }
        all_s[rr] += exa;
        pos_s[rr] += ispos ? ex : 0.f;
        pos_m[rr]  = fmaxf(pos_m[rr], ispos ? z : -INFINITY);
        const float sn = same ? -INFINITY : z;           // self is same -> excluded
        ins3(t0[rr], t1[rr], t2[rr], sn);
      }
    }
  };

  // one pipeline step; counted vmcnt: 4 in steady state (tiles t+2,t+3 in
  // flight = 4 loads), 2 at NITER-3, 0 at NITER-2 (tail).
  auto step = [&](int t, const short8* CUR, short8* N3){
    if (t + 3 < NITER) stage(N3, t + 3);
    compute(CUR, t);
    if (t < NITER - 3)       asm volatile("s_waitcnt vmcnt(4)" ::: "memory");
    else if (t == NITER - 3) asm volatile("s_waitcnt vmcnt(2)" ::: "memory");
    else                     asm volatile("s_waitcnt vmcnt(0)" ::: "memory");
    __builtin_amdgcn_s_barrier();
  };

  // prologue drain: buf0..2 landed, labs written, A/labr loaded -> count=0
  asm volatile("s_waitcnt vmcnt(0) lgkmcnt(0)" ::: "memory");
  __builtin_amdgcn_s_barrier();

  for (int mt = 0; mt < NITER; mt += 4){
    step(mt + 0, Bs0, Bs3);   // stages (mt+3)&3 == 3
    step(mt + 1, Bs1, Bs0);
    step(mt + 2, Bs2, Bs1);
    step(mt + 3, Bs3, Bs2);
  }

  // butterfly reduce over the 16 column-classes (disjoint-set merge: exact)
  #pragma unroll
  for (int mask = 1; mask < 16; mask <<= 1){
    #pragma unroll
    for (int s = 0; s < 4; ++s){
      all_s[s] += __shfl_xor(all_s[s], mask, 64);
      pos_s[s] += __shfl_xor(pos_s[s], mask, 64);
      pos_m[s]  = fmaxf(pos_m[s], __shfl_xor(pos_m[s], mask, 64));
      float b0 = __shfl_xor(t0[s], mask, 64);
      float b1 = __shfl_xor(t1[s], mask, 64);
      float b2 = __shfl_xor(t2[s], mask, 64);
      ins3(t0[s], t1[s], t2[s], b0);
      ins3(t0[s], t1[s], t2[s], b1);
      ins3(t0[s], t1[s], t2[s], b2);
    }
  }

  if (l == 0){
    #pragma unroll
    for (int s = 0; s < 4; ++s){
      const int grow = row0 + q * 4 + s;
      float* p = partials + ((size_t)grow * NSTRIP + strip) * 6;
      p[0] = all_s[s]; p[1] = pos_s[s]; p[2] = pos_m[s];
      p[3] = t0[s];    p[4] = t1[s];    p[5] = t2[s];
    }
  }
}

// ---- kernel 3: merge strips per row, per-row losses, reduce, fused final.
// One wave per block; last block (atomic counter) computes the scalar output.
__global__ void merge_kernel(const float* __restrict__ partials,
                             float* __restrict__ accum,
                             float* __restrict__ out){
  const int row = blockIdx.x * 64 + threadIdx.x;
  float all_s = 0.f, pos_s = 0.f, pos_m = -INFINITY;
  float t0 = -INFINITY, t1 = -INFINITY, t2 = -INFINITY;
  #pragma unroll
  for (int s = 0; s < NSTRIP; ++s){
    const float* p = partials + ((size_t)row * NSTRIP + s) * 6;
    all_s += p[0]; pos_s += p[1];
    pos_m = fmaxf(pos_m, p[2]);
    ins3(t0, t1, t2, p[3]); ins3(t0, t1, t2, p[4]); ins3(t0, t1, t2, p[5]);
  }
  const bool has_pos = pos_m > -INFINITY;
  float vb = 0.f, vh = 0.f, vhp = 0.f, vm = 0.f, vv = 0.f;
  if (has_pos){
    vhp = 1.f;
    vb  = -logf(pos_s / (all_s + 1e-10f) + 1e-10f);
    const float hnm = (t0 + t1 + t2) * (1.f/3.f);       // z-space
    vh  = fmaxf((hnm - pos_m) * LN2 + MARGIN, 0.f);     // relu; -inf -> 0
    if (t0 > -INFINITY){
      vv = 1.f;
      vm = fmaxf((t0 - pos_m) * LN2 + MARGIN, 0.f);
    }
  }
  float vals[5] = {vb, vh, vhp, vm, vv};
  #pragma unroll
  for (int m = 1; m < 64; m <<= 1)
    #pragma unroll
    for (int i = 0; i < 5; ++i) vals[i] += __shfl_xor(vals[i], m, 64);
  if (threadIdx.x == 0){
    #pragma unroll
    for (int i = 0; i < 5; ++i) atomicAdd(&accum[i], vals[i]);
    __threadfence();
    const unsigned prev = atomicAdd((unsigned int*)&accum[7], 1u);
    if (prev == (unsigned)(gridDim.x - 1)){
      // all blocks' device-scope adds complete; read via atomics (coherent)
      const float a0 = atomicAdd(&accum[0], 0.f);
      const float a1 = atomicAdd(&accum[1], 0.f);
      const float a2 = atomicAdd(&accum[2], 0.f);
      const float a3 = atomicAdd(&accum[3], 0.f);
      const float a4 = atomicAdd(&accum[4], 0.f);
      const float nhp   = fmaxf(a2, 1.f);
      const float basic = a0 / nhp;
      const float hard  = a1 / nhp;
      const float marg  = (a4 > 0.f) ? (a3 / fmaxf(a4, 1.f)) : 0.f;
      out[0] = basic + 0.5f * hard + 0.1f * marg;
    }
  }
}

extern "C" void kernel_launch(void* const* d_in, const int* in_sizes, int n_in,
                              void* d_out, int out_size, void* d_ws, size_t ws_size,
                              hipStream_t stream){
  const float* emb  = (const float*)d_in[0];
  const int* labels = (const int*)d_in[1];
  float* out        = (float*)d_out;
  char* ws          = (char*)d_ws;

  unsigned short* E = (unsigned short*)ws;                              // 4 MiB bf16
  const size_t E_BYTES = (size_t)BATCH * DIM * 2;
  float* partials   = (float*)(ws + E_BYTES);                           // 1.5 MiB
  const size_t P_BYTES = (size_t)BATCH * NSTRIP * 6 * sizeof(float);
  float* accum      = (float*)(ws + E_BYTES + P_BYTES);                 // 8 floats

  norm_cast_kernel<<<BATCH/4, 256, 0, stream>>>(emb, E, accum);
  sim_stats_kernel<<<dim3(NSTRIP, BATCH/MROWS), 512, 0, stream>>>(E, labels, partials);
  merge_kernel<<<BATCH/64, 64, 0, stream>>>(partials, accum, out);
}

// Round 14
// 146.239 us; speedup vs baseline: 1.0132x; 1.0132x over previous
//
#include <hip/hip_runtime.h>
#include <cstdint>
#include <cstddef>

#define BATCH  8192
#define DIM    256
#define NSTRIP 16
#define SCOLS  512            // columns per strip
#define MROWS  256            // rows per block (8 waves x 32 rows)
#define NTILE  64             // cols per inner iteration
#define NITER  (SCOLS/NTILE)  // 8

static constexpr float EXP2_SC = 1.4426950408889634f / 0.07f;  // log2(e)/T
static constexpr float LN2     = 0.6931471805599453f;          // sim = z * LN2
static constexpr float MARGIN  = 0.2f;

typedef __attribute__((ext_vector_type(8))) short short8;
typedef __attribute__((ext_vector_type(4))) float f32x4;

__device__ __forceinline__ unsigned short f2bf(float f){
  unsigned int u = __float_as_uint(f);
  u += 0x7FFFu + ((u >> 16) & 1u);     // round-to-nearest-even
  return (unsigned short)(u >> 16);
}

__device__ __forceinline__ float med3f(float a, float b, float c){
  float r;
  asm("v_med3_f32 %0, %1, %2, %3" : "=v"(r) : "v"(a), "v"(b), "v"(c));
  return r;
}

// insert s into sorted t0>=t1>=t2, keep top-3: 3 VALU ops (max + 2 med3)
__device__ __forceinline__ void ins3(float& t0, float& t1, float& t2, float s){
  const float r1 = med3f(s, t0, t1);   // uses old t0,t1
  const float r2 = med3f(s, t1, t2);   // uses old t1,t2
  t0 = fmaxf(t0, s);
  t1 = r1; t2 = r2;
}

// ---- kernel 1: L2-normalize rows (fp32), cast to bf16; zero scalar accumulators
__global__ void norm_cast_kernel(const float* __restrict__ emb,
                                 unsigned short* __restrict__ E,
                                 float* __restrict__ accum){
  if (blockIdx.x == 0 && threadIdx.x < 8) accum[threadIdx.x] = 0.0f;
  const int wave = threadIdx.x >> 6;
  const int lane = threadIdx.x & 63;
  const int row  = blockIdx.x * 4 + wave;
  const float4 v = *(const float4*)(emb + (size_t)row * DIM + lane * 4);
  float ss = v.x*v.x + v.y*v.y + v.z*v.z + v.w*v.w;
  #pragma unroll
  for (int m = 1; m < 64; m <<= 1) ss += __shfl_xor(ss, m, 64);
  float nrm = fmaxf(sqrtf(ss), 1e-12f);
  float inv = 1.0f / nrm;
  ushort4 o;
  o.x = f2bf(v.x * inv); o.y = f2bf(v.y * inv);
  o.z = f2bf(v.z * inv); o.w = f2bf(v.w * inv);
  *(ushort4*)(E + (size_t)row * DIM + lane * 4) = o;
}

// ---- kernel 2: fused sim-tile GEMM (bf16 MFMA) + online per-row statistics.
// The untested matrix cell: 32 rows/wave (each B fragment feeds 2 MFMAs ->
// half the ds_read bytes of R6) AT 16 waves/CU (R6's wave count, which R10
// lacked). 512 thr = 8 waves x 32 rows = 256 rows/block; grid (16,32) = 512
// blocks = 2 blocks/CU exact (LDS 66KB). Body = R10's verified math
// (absmax 0.0, VGPR=120 <= 128 so 4 waves/SIMD); pipeline = R6's verified
// double-buffer prefetch with raw barrier + full waitcnt.
__global__ __launch_bounds__(512, 2)
void sim_stats_kernel(const unsigned short* __restrict__ E,
                      const int* __restrict__ labels,
                      float* __restrict__ partials){
  const int strip = blockIdx.x;
  const int cs    = strip * SCOLS;
  const int tid   = threadIdx.x;
  const int wave  = tid >> 6;
  const int lane  = tid & 63;
  const int l     = lane & 15;   // column within 16-wide subtile
  const int q     = lane >> 4;   // quad: selects k-group and C row group

  // B buffers: [chunk c=(kk*4+q)][col r 0..63] of 8 bf16 (16B each)
  __shared__ short8 Bs0[32 * 64];   // 32 KiB
  __shared__ short8 Bs1[32 * 64];   // 32 KiB
  __shared__ int labs[SCOLS];       // 2 KiB

  for (int i = tid; i < SCOLS; i += 512) labs[i] = labels[cs + i];

  const int row0 = blockIdx.y * MROWS + wave * 32;

  // async stage of one 64-col tile (32KB = 2048x16B): 4 insts/wave (8 waves
  // x 4 chunks); lane gathers sim-col cb+lane of chunk c = wave*4+ci.
  // Verified zero-conflict form: per-chunk addr, offset=0; LDS dst =
  // wave-uniform base + lane*16.
  auto stage = [&](short8* dstBuf, int it){
    const int cb = cs + it * NTILE;
    #pragma unroll
    for (int ci = 0; ci < 4; ++ci){
      const int c = wave * 4 + ci;
      const unsigned short* g = E + (size_t)(cb + lane) * DIM + c * 8;
      __builtin_amdgcn_global_load_lds(
        (const __attribute__((address_space(1))) unsigned int*)g,
        (__attribute__((address_space(3))) unsigned int*)&dstBuf[c * 64],
        16, 0, 0);
    }
  };

  stage(Bs0, 0);   // tile 0 in flight during A-fragment/label loads

  // A fragments for the wave's 32 rows, full K=256, in registers (64 VGPR).
  short8 a[2][8];
  #pragma unroll
  for (int rt = 0; rt < 2; ++rt){
    const unsigned short* rp = E + (size_t)(row0 + rt*16 + l) * DIM + q * 8;
    #pragma unroll
    for (int kk = 0; kk < 8; ++kk)
      a[rt][kk] = *(const short8*)(rp + kk * 32);
  }

  int labr[2][4];
  #pragma unroll
  for (int rt = 0; rt < 2; ++rt)
    #pragma unroll
    for (int rr = 0; rr < 4; ++rr)
      labr[rt][rr] = labels[row0 + rt*16 + q*4 + rr];

  float all_s[8], pos_s[8], pos_m[8], t0[8], t1[8], t2[8];
  #pragma unroll
  for (int s = 0; s < 8; ++s){
    all_s[s] = 0.f; pos_s[s] = 0.f;
    pos_m[s] = -INFINITY; t0[s] = -INFINITY; t1[s] = -INFINITY; t2[s] = -INFINITY;
  }

  auto compute = [&](const short8* B, int it){
    const int cb = cs + it * NTILE;
    #pragma unroll
    for (int t = 0; t < 4; ++t){
      const int c0   = cb + t * 16;
      const int labc = labs[it * NTILE + t * 16 + l];
      f32x4 acc0 = {0.f,0.f,0.f,0.f};
      f32x4 acc1 = {0.f,0.f,0.f,0.f};
      #pragma unroll
      for (int kk = 0; kk < 8; ++kk){
        short8 b = B[(kk * 4 + q) * 64 + t * 16 + l];   // read ONCE, 2 MFMAs
        acc0 = __builtin_amdgcn_mfma_f32_16x16x32_bf16(a[0][kk], b, acc0, 0, 0, 0);
        acc1 = __builtin_amdgcn_mfma_f32_16x16x32_bf16(a[1][kk], b, acc1, 0, 0, 0);
      }
      // wave-uniform: does this 16-col subtile intersect the wave's 32 rows?
      const bool selfT = (c0 < row0 + 32) && (row0 < c0 + 16);
      #pragma unroll
      for (int rt = 0; rt < 2; ++rt){
        #pragma unroll
        for (int rr = 0; rr < 4; ++rr){
          const float d  = rt ? acc1[rr] : acc0[rr];
          const int   s  = rt * 4 + rr;
          const float z  = d * EXP2_SC;                    // z-space maxima
          const float ex = __builtin_amdgcn_exp2f(z);
          const bool same = (labc == labr[rt][rr]);
          bool  ispos = same;
          float exa   = ex;
          if (selfT){
            const int grow = row0 + rt * 16 + q * 4 + rr;
            const bool self = (c0 + l == grow);
            ispos = same && !self;
            exa   = self ? 0.f : ex;
          }
          all_s[s] += exa;
          pos_s[s] += ispos ? ex : 0.f;
          pos_m[s]  = fmaxf(pos_m[s], ispos ? z : -INFINITY);
          const float sn = same ? -INFINITY : z;           // self is same -> excluded
          ins3(t0[s], t1[s], t2[s], sn);
        }
      }
    }
  };

  // prologue: tile 0 landed (all waves), labs written
  asm volatile("s_waitcnt vmcnt(0) lgkmcnt(0)" ::: "memory");
  __builtin_amdgcn_s_barrier();

  for (int it = 0; it < NITER; ++it){
    const short8* cur = (it & 1) ? Bs1 : Bs0;
    short8*       nxt = (it & 1) ? Bs0 : Bs1;
    if (it + 1 < NITER) stage(nxt, it + 1);   // prefetch flies under compute
    compute(cur, it);
    // my prefetch landed; barrier => everyone's landed AND everyone done
    // reading cur (so next iter may restage it)
    asm volatile("s_waitcnt vmcnt(0) lgkmcnt(0)" ::: "memory");
    __builtin_amdgcn_s_barrier();
  }

  // butterfly reduce over the 16 column-classes (disjoint-set merge: exact)
  #pragma unroll
  for (int mask = 1; mask < 16; mask <<= 1){
    #pragma unroll
    for (int s = 0; s < 8; ++s){
      all_s[s] += __shfl_xor(all_s[s], mask, 64);
      pos_s[s] += __shfl_xor(pos_s[s], mask, 64);
      pos_m[s]  = fmaxf(pos_m[s], __shfl_xor(pos_m[s], mask, 64));
      float b0 = __shfl_xor(t0[s], mask, 64);
      float b1 = __shfl_xor(t1[s], mask, 64);
      float b2 = __shfl_xor(t2[s], mask, 64);
      ins3(t0[s], t1[s], t2[s], b0);
      ins3(t0[s], t1[s], t2[s], b1);
      ins3(t0[s], t1[s], t2[s], b2);
    }
  }

  if (l == 0){
    #pragma unroll
    for (int s = 0; s < 8; ++s){
      const int grow = row0 + (s >> 2) * 16 + q * 4 + (s & 3);
      float* p = partials + ((size_t)grow * NSTRIP + strip) * 6;
      p[0] = all_s[s]; p[1] = pos_s[s]; p[2] = pos_m[s];
      p[3] = t0[s];    p[4] = t1[s];    p[5] = t2[s];
    }
  }
}

// ---- kernel 3: merge strips per row, per-row losses, reduce, fused final.
// One wave per block; last block (atomic counter) computes the scalar output.
__global__ void merge_kernel(const float* __restrict__ partials,
                             float* __restrict__ accum,
                             float* __restrict__ out){
  const int row = blockIdx.x * 64 + threadIdx.x;
  float all_s = 0.f, pos_s = 0.f, pos_m = -INFINITY;
  float t0 = -INFINITY, t1 = -INFINITY, t2 = -INFINITY;
  #pragma unroll
  for (int s = 0; s < NSTRIP; ++s){
    const float* p = partials + ((size_t)row * NSTRIP + s) * 6;
    all_s += p[0]; pos_s += p[1];
    pos_m = fmaxf(pos_m, p[2]);
    ins3(t0, t1, t2, p[3]); ins3(t0, t1, t2, p[4]); ins3(t0, t1, t2, p[5]);
  }
  const bool has_pos = pos_m > -INFINITY;
  float vb = 0.f, vh = 0.f, vhp = 0.f, vm = 0.f, vv = 0.f;
  if (has_pos){
    vhp = 1.f;
    vb  = -logf(pos_s / (all_s + 1e-10f) + 1e-10f);
    const float hnm = (t0 + t1 + t2) * (1.f/3.f);       // z-space
    vh  = fmaxf((hnm - pos_m) * LN2 + MARGIN, 0.f);     // relu; -inf -> 0
    if (t0 > -INFINITY){
      vv = 1.f;
      vm = fmaxf((t0 - pos_m) * LN2 + MARGIN, 0.f);
    }
  }
  float vals[5] = {vb, vh, vhp, vm, vv};
  #pragma unroll
  for (int m = 1; m < 64; m <<= 1)
    #pragma unroll
    for (int i = 0; i < 5; ++i) vals[i] += __shfl_xor(vals[i], m, 64);
  if (threadIdx.x == 0){
    #pragma unroll
    for (int i = 0; i < 5; ++i) atomicAdd(&accum[i], vals[i]);
    __threadfence();
    const unsigned prev = atomicAdd((unsigned int*)&accum[7], 1u);
    if (prev == (unsigned)(gridDim.x - 1)){
      // all blocks' device-scope adds complete; read via atomics (coherent)
      const float a0 = atomicAdd(&accum[0], 0.f);
      const float a1 = atomicAdd(&accum[1], 0.f);
      const float a2 = atomicAdd(&accum[2], 0.f);
      const float a3 = atomicAdd(&accum[3], 0.f);
      const float a4 = atomicAdd(&accum[4], 0.f);
      const float nhp   = fmaxf(a2, 1.f);
      const float basic = a0 / nhp;
      const float hard  = a1 / nhp;
      const float marg  = (a4 > 0.f) ? (a3 / fmaxf(a4, 1.f)) : 0.f;
      out[0] = basic + 0.5f * hard + 0.1f * marg;
    }
  }
}

extern "C" void kernel_launch(void* const* d_in, const int* in_sizes, int n_in,
                              void* d_out, int out_size, void* d_ws, size_t ws_size,
                              hipStream_t stream){
  const float* emb  = (const float*)d_in[0];
  const int* labels = (const int*)d_in[1];
  float* out        = (float*)d_out;
  char* ws          = (char*)d_ws;

  unsigned short* E = (unsigned short*)ws;                              // 4 MiB bf16
  const size_t E_BYTES = (size_t)BATCH * DIM * 2;
  float* partials   = (float*)(ws + E_BYTES);                           // 3 MiB
  const size_t P_BYTES = (size_t)BATCH * NSTRIP * 6 * sizeof(float);
  float* accum      = (float*)(ws + E_BYTES + P_BYTES);                 // 8 floats

  norm_cast_kernel<<<BATCH/4, 256, 0, stream>>>(emb, E, accum);
  sim_stats_kernel<<<dim3(NSTRIP, BATCH/MROWS), 512, 0, stream>>>(E, labels, partials);
  merge_kernel<<<BATCH/64, 64, 0, stream>>>(partials, accum, out);
}

// Round 15
// 135.521 us; speedup vs baseline: 1.0934x; 1.0791x over previous
//
#include <hip/hip_runtime.h>
#include <cstdint>
#include <cstddef>

#define BATCH  8192
#define DIM    256
#define NSTRIP 8
#define SCOLS  1024           // columns per strip
#define MROWS  128            // rows per block (8 waves x 16 rows)
#define NTILE  64             // cols per inner iteration
#define NITER  (SCOLS/NTILE)  // 16

static constexpr float EXP2_SC = 1.4426950408889634f / 0.07f;  // log2(e)/T
static constexpr float LN2     = 0.6931471805599453f;          // sim = z * LN2
static constexpr float MARGIN  = 0.2f;

typedef __attribute__((ext_vector_type(8))) short short8;
typedef __attribute__((ext_vector_type(4))) float f32x4;

__device__ __forceinline__ unsigned short f2bf(float f){
  unsigned int u = __float_as_uint(f);
  u += 0x7FFFu + ((u >> 16) & 1u);     // round-to-nearest-even
  return (unsigned short)(u >> 16);
}

__device__ __forceinline__ float med3f(float a, float b, float c){
  float r;
  asm("v_med3_f32 %0, %1, %2, %3" : "=v"(r) : "v"(a), "v"(b), "v"(c));
  return r;
}

// insert s into sorted t0>=t1>=t2, keep top-3: 3 VALU ops (max + 2 med3)
__device__ __forceinline__ void ins3(float& t0, float& t1, float& t2, float s){
  const float r1 = med3f(s, t0, t1);   // uses old t0,t1
  const float r2 = med3f(s, t1, t2);   // uses old t1,t2
  t0 = fmaxf(t0, s);
  t1 = r1; t2 = r2;
}

// ---- kernel 1: L2-normalize rows (fp32), cast to bf16; zero scalar accumulators
__global__ void norm_cast_kernel(const float* __restrict__ emb,
                                 unsigned short* __restrict__ E,
                                 float* __restrict__ accum){
  if (blockIdx.x == 0 && threadIdx.x < 8) accum[threadIdx.x] = 0.0f;
  const int wave = threadIdx.x >> 6;
  const int lane = threadIdx.x & 63;
  const int row  = blockIdx.x * 4 + wave;
  const float4 v = *(const float4*)(emb + (size_t)row * DIM + lane * 4);
  float ss = v.x*v.x + v.y*v.y + v.z*v.z + v.w*v.w;
  #pragma unroll
  for (int m = 1; m < 64; m <<= 1) ss += __shfl_xor(ss, m, 64);
  float nrm = fmaxf(sqrtf(ss), 1e-12f);
  float inv = 1.0f / nrm;
  ushort4 o;
  o.x = f2bf(v.x * inv); o.y = f2bf(v.y * inv);
  o.z = f2bf(v.z * inv); o.w = f2bf(v.w * inv);
  *(ushort4*)(E + (size_t)row * DIM + lane * 4) = o;
}

// ---- kernel 2: fused sim-tile GEMM (bf16 MFMA) + online per-row statistics.
// 512 threads = 8 waves, 16 rows/wave; grid (8,64)=512 blocks = 1 generation
// at 2 blocks/CU (LDS 68KB) -> 16 waves/CU. Double-buffered staging with
// prefetch-before-compute pipeline: stage(next) issued BEFORE compute(cur);
// raw s_barrier with asm waitcnt so load latency hides under compute.
// SESSION BEST (R6): sim_stats 72.2us, total 136.6us. Eight structural
// alternatives (occupancy x2, LDS-volume /2, coalesced staging, ring-4
// counted vmcnt, cooperative fusion) all measured 77-117us — this is the
// empirical optimum of the reachable schedule space.
__global__ __launch_bounds__(512, 4)
void sim_stats_kernel(const unsigned short* __restrict__ E,
                      const int* __restrict__ labels,
                      float* __restrict__ partials){
  const int strip = blockIdx.x;
  const int cs    = strip * SCOLS;
  const int tid   = threadIdx.x;
  const int wave  = tid >> 6;
  const int lane  = tid & 63;
  const int l     = lane & 15;   // column within 16-wide subtile
  const int q     = lane >> 4;   // quad: selects k-group and C row group

  // B buffers: [chunk c=(kk*4+q)][col r 0..63] of 8 bf16 (16B each)
  __shared__ short8 Bs0[32 * 64];   // 32 KiB
  __shared__ short8 Bs1[32 * 64];   // 32 KiB
  __shared__ int labs[SCOLS];       // 4 KiB

  for (int i = tid; i < SCOLS; i += 512) labs[i] = labels[cs + i];

  const int row0 = blockIdx.y * MROWS + wave * 16;

  // async stage of one 64-col tile: wave w stages chunks w*4..w*4+3,
  // lane gathers sim-col cb+lane (verified form: per-chunk addr, offset=0)
  auto stage = [&](short8* dstBuf, int it){
    const int cb = cs + it * NTILE;
    #pragma unroll
    for (int ci = 0; ci < 4; ++ci){
      const int c = wave * 4 + ci;
      const unsigned short* g = E + (size_t)(cb + lane) * DIM + c * 8;
      __builtin_amdgcn_global_load_lds(
        (const __attribute__((address_space(1))) unsigned int*)g,
        (__attribute__((address_space(3))) unsigned int*)&dstBuf[c * 64],
        16, 0, 0);
    }
  };

  stage(Bs0, 0);   // tile 0 in flight during A-fragment/label loads

  // A fragments for the wave's 16 rows, full K=256, kept in registers (32 VGPR).
  short8 a[8];
  {
    const unsigned short* rp = E + (size_t)(row0 + l) * DIM + q * 8;
    #pragma unroll
    for (int kk = 0; kk < 8; ++kk)
      a[kk] = *(const short8*)(rp + kk * 32);
  }

  int labr[4];
  #pragma unroll
  for (int rr = 0; rr < 4; ++rr)
    labr[rr] = labels[row0 + q * 4 + rr];

  float all_s[4], pos_s[4], pos_m[4], t0[4], t1[4], t2[4];
  #pragma unroll
  for (int s = 0; s < 4; ++s){
    all_s[s] = 0.f; pos_s[s] = 0.f;
    pos_m[s] = -INFINITY; t0[s] = -INFINITY; t1[s] = -INFINITY; t2[s] = -INFINITY;
  }

  auto compute = [&](const short8* B, int it){
    const int cb = cs + it * NTILE;
    #pragma unroll
    for (int t = 0; t < 4; ++t){
      const int c0   = cb + t * 16;
      const int labc = labs[it * NTILE + t * 16 + l];
      f32x4 acc = {0.f,0.f,0.f,0.f};
      #pragma unroll
      for (int kk = 0; kk < 8; ++kk){
        short8 b = B[(kk * 4 + q) * 64 + t * 16 + l];
        acc = __builtin_amdgcn_mfma_f32_16x16x32_bf16(a[kk], b, acc, 0, 0, 0);
      }
      // wave-uniform: 16-aligned subtile hits the wave's 16 rows iff equal
      const bool selfT = (c0 == row0);
      #pragma unroll
      for (int rr = 0; rr < 4; ++rr){
        const float d  = acc[rr];
        const float z  = d * EXP2_SC;                    // z-space maxima
        const float ex = __builtin_amdgcn_exp2f(z);
        const bool same = (labc == labr[rr]);
        bool  ispos = same;
        float exa   = ex;
        if (selfT){
          const int grow = row0 + q * 4 + rr;
          const bool self = (c0 + l == grow);
          ispos = same && !self;
          exa   = self ? 0.f : ex;
        }
        all_s[rr] += exa;
        pos_s[rr] += ispos ? ex : 0.f;
        pos_m[rr]  = fmaxf(pos_m[rr], ispos ? z : -INFINITY);
        const float sn = same ? -INFINITY : z;           // self is same -> excluded
        ins3(t0[rr], t1[rr], t2[rr], sn);
      }
    }
  };

  // prologue: tile 0 landed (all waves), labs written
  asm volatile("s_waitcnt vmcnt(0) lgkmcnt(0)" ::: "memory");
  __builtin_amdgcn_s_barrier();

  for (int it = 0; it < NITER; ++it){
    const short8* cur = (it & 1) ? Bs1 : Bs0;
    short8*       nxt = (it & 1) ? Bs0 : Bs1;
    if (it + 1 < NITER) stage(nxt, it + 1);   // prefetch flies under compute
    compute(cur, it);
    // my prefetch landed; barrier => everyone's landed AND everyone done
    // reading cur (so next iter may restage it)
    asm volatile("s_waitcnt vmcnt(0) lgkmcnt(0)" ::: "memory");
    __builtin_amdgcn_s_barrier();
  }

  // butterfly reduce over the 16 column-classes (disjoint-set merge: exact)
  #pragma unroll
  for (int mask = 1; mask < 16; mask <<= 1){
    #pragma unroll
    for (int s = 0; s < 4; ++s){
      all_s[s] += __shfl_xor(all_s[s], mask, 64);
      pos_s[s] += __shfl_xor(pos_s[s], mask, 64);
      pos_m[s]  = fmaxf(pos_m[s], __shfl_xor(pos_m[s], mask, 64));
      float b0 = __shfl_xor(t0[s], mask, 64);
      float b1 = __shfl_xor(t1[s], mask, 64);
      float b2 = __shfl_xor(t2[s], mask, 64);
      ins3(t0[s], t1[s], t2[s], b0);
      ins3(t0[s], t1[s], t2[s], b1);
      ins3(t0[s], t1[s], t2[s], b2);
    }
  }

  if (l == 0){
    #pragma unroll
    for (int s = 0; s < 4; ++s){
      const int grow = row0 + q * 4 + s;
      float* p = partials + ((size_t)grow * NSTRIP + strip) * 6;
      p[0] = all_s[s]; p[1] = pos_s[s]; p[2] = pos_m[s];
      p[3] = t0[s];    p[4] = t1[s];    p[5] = t2[s];
    }
  }
}

// ---- kernel 3: merge strips per row, per-row losses, reduce, fused final.
// One wave per block; last block (atomic counter) computes the scalar output.
__global__ void merge_kernel(const float* __restrict__ partials,
                             float* __restrict__ accum,
                             float* __restrict__ out){
  const int row = blockIdx.x * 64 + threadIdx.x;
  float all_s = 0.f, pos_s = 0.f, pos_m = -INFINITY;
  float t0 = -INFINITY, t1 = -INFINITY, t2 = -INFINITY;
  #pragma unroll
  for (int s = 0; s < NSTRIP; ++s){
    const float* p = partials + ((size_t)row * NSTRIP + s) * 6;
    all_s += p[0]; pos_s += p[1];
    pos_m = fmaxf(pos_m, p[2]);
    ins3(t0, t1, t2, p[3]); ins3(t0, t1, t2, p[4]); ins3(t0, t1, t2, p[5]);
  }
  const bool has_pos = pos_m > -INFINITY;
  float vb = 0.f, vh = 0.f, vhp = 0.f, vm = 0.f, vv = 0.f;
  if (has_pos){
    vhp = 1.f;
    vb  = -logf(pos_s / (all_s + 1e-10f) + 1e-10f);
    const float hnm = (t0 + t1 + t2) * (1.f/3.f);       // z-space
    vh  = fmaxf((hnm - pos_m) * LN2 + MARGIN, 0.f);     // relu; -inf -> 0
    if (t0 > -INFINITY){
      vv = 1.f;
      vm = fmaxf((t0 - pos_m) * LN2 + MARGIN, 0.f);
    }
  }
  float vals[5] = {vb, vh, vhp, vm, vv};
  #pragma unroll
  for (int m = 1; m < 64; m <<= 1)
    #pragma unroll
    for (int i = 0; i < 5; ++i) vals[i] += __shfl_xor(vals[i], m, 64);
  if (threadIdx.x == 0){
    #pragma unroll
    for (int i = 0; i < 5; ++i) atomicAdd(&accum[i], vals[i]);
    __threadfence();
    const unsigned prev = atomicAdd((unsigned int*)&accum[7], 1u);
    if (prev == (unsigned)(gridDim.x - 1)){
      // all blocks' device-scope adds complete; read via atomics (coherent)
      const float a0 = atomicAdd(&accum[0], 0.f);
      const float a1 = atomicAdd(&accum[1], 0.f);
      const float a2 = atomicAdd(&accum[2], 0.f);
      const float a3 = atomicAdd(&accum[3], 0.f);
      const float a4 = atomicAdd(&accum[4], 0.f);
      const float nhp   = fmaxf(a2, 1.f);
      const float basic = a0 / nhp;
      const float hard  = a1 / nhp;
      const float marg  = (a4 > 0.f) ? (a3 / fmaxf(a4, 1.f)) : 0.f;
      out[0] = basic + 0.5f * hard + 0.1f * marg;
    }
  }
}

extern "C" void kernel_launch(void* const* d_in, const int* in_sizes, int n_in,
                              void* d_out, int out_size, void* d_ws, size_t ws_size,
                              hipStream_t stream){
  const float* emb  = (const float*)d_in[0];
  const int* labels = (const int*)d_in[1];
  float* out        = (float*)d_out;
  char* ws          = (char*)d_ws;

  unsigned short* E = (unsigned short*)ws;                              // 4 MiB bf16
  const size_t E_BYTES = (size_t)BATCH * DIM * 2;
  float* partials   = (float*)(ws + E_BYTES);                           // 1.5 MiB
  const size_t P_BYTES = (size_t)BATCH * NSTRIP * 6 * sizeof(float);
  float* accum      = (float*)(ws + E_BYTES + P_BYTES);                 // 8 floats

  norm_cast_kernel<<<BATCH/4, 256, 0, stream>>>(emb, E, accum);
  sim_stats_kernel<<<dim3(NSTRIP, BATCH/MROWS), 512, 0, stream>>>(E, labels, partials);
  merge_kernel<<<BATCH/64, 64, 0, stream>>>(partials, accum, out);
}